// Round 17
// baseline (344.237 us; speedup 1.0000x reference)
//
#include <hip/hip_runtime.h>
#include <hip/hip_bf16.h>

#define TSEQ 2048
#define HID 384
#define NHEAD 4
#define HD 96
#define NBATCH 8

using bf16 = __bf16;
typedef bf16 bf16x8 __attribute__((ext_vector_type(8)));
typedef bf16 bf16x4 __attribute__((ext_vector_type(4)));
typedef float f32x4 __attribute__((ext_vector_type(4)));
typedef unsigned long long u64;

static __device__ __forceinline__ f32x4 mfma16(bf16x8 a, bf16x8 b, f32x4 c) {
    return __builtin_amdgcn_mfma_f32_16x16x32_bf16(a, b, c, 0, 0, 0);
}

// same-wave LDS handoff: wait ds ops without draining vmcnt; DS pinned both
// sides, VMEM/VALU/MFMA may cross (mask 0x7F = all but DS*).
#define LDS_HANDOFF()                                   \
    __builtin_amdgcn_sched_barrier(0x7F);               \
    asm volatile("s_waitcnt lgkmcnt(0)");               \
    __builtin_amdgcn_sched_barrier(0x7F)

// async global->LDS DMA, 16B per lane; LDS dest = wave-uniform base + lane*16.
#define GL2LDS(g, l) __builtin_amdgcn_global_load_lds(                        \
    (const __attribute__((address_space(1))) unsigned int*)(const void*)(g),  \
    (__attribute__((address_space(3))) unsigned int*)(void*)(l), 16, 0, 0)

// ---------------- conversion kernels ----------------
__global__ void k_conv8(const float* __restrict__ src, bf16* __restrict__ dst, int n8) {
    int t = blockIdx.x * 256 + threadIdx.x;
    if (t >= n8) return;
    const float4* s4 = reinterpret_cast<const float4*>(src);
    float4 a = s4[2 * t], b = s4[2 * t + 1];
    bf16x8 o;
    o[0] = (bf16)a.x; o[1] = (bf16)a.y; o[2] = (bf16)a.z; o[3] = (bf16)a.w;
    o[4] = (bf16)b.x; o[5] = (bf16)b.y; o[6] = (bf16)b.z; o[7] = (bf16)b.w;
    *reinterpret_cast<bf16x8*>(dst + 8 * t) = o;
}

__global__ void k_convT5(const float* __restrict__ W0, const float* __restrict__ W1,
                         const float* __restrict__ W2, const float* __restrict__ W3,
                         const float* __restrict__ W4,
                         bf16* __restrict__ T0, bf16* __restrict__ T1,
                         bf16* __restrict__ T2, bf16* __restrict__ T3,
                         bf16* __restrict__ T4) {
    int t = blockIdx.x * 256 + threadIdx.x;  // T[n][k] = W[k][n]
    int which = blockIdx.y;
    const float* W = (which == 0) ? W0 : (which == 1) ? W1 : (which == 2) ? W2
                     : (which == 3) ? W3 : W4;
    bf16* T = (which == 0) ? T0 : (which == 1) ? T1 : (which == 2) ? T2
              : (which == 3) ? T3 : T4;
    int n = t / HID, k = t % HID;
    T[t] = (bf16)W[(size_t)k * HID + n];
}

// ---------------- projection GEMM (Q,K,V,pos), A-panel-in-LDS ----------------
// grid (256, 4mats): block stages the 64x384 A-panel ONCE; each wave owns one
// head's 96 cols and streams WT B-frags directly from L2 (WT 288KB, resident).
// A-traffic 197->49MB, blocks 4096->1024.
__launch_bounds__(256, 2)
__global__ void k_proj(const bf16* __restrict__ X, const bf16* __restrict__ P,
                       const bf16* __restrict__ wqT, const bf16* __restrict__ wkT,
                       const bf16* __restrict__ wvT, const bf16* __restrict__ wpT,
                       const float* __restrict__ bq, const float* __restrict__ bk,
                       const float* __restrict__ bv,
                       const float* __restrict__ pbu, const float* __restrict__ pbv,
                       bf16* __restrict__ qu, bf16* __restrict__ qv,
                       bf16* __restrict__ kws, bf16* __restrict__ vt,
                       bf16* __restrict__ pp) {
    __shared__ bf16 a_lds[64][392];
    const float SC = 0.10206207262f;  // 1/sqrt(96) folded into q
    int mat = blockIdx.y;             // 0=Q 1=K 2=V 3=POS
    int m0 = blockIdx.x * 64;
    if (mat == 3 && m0 >= 4095) return;
    const bf16* A  = (mat == 3) ? P : X;
    const bf16* WT = (mat == 0) ? wqT : (mat == 1) ? wkT : (mat == 2) ? wvT : wpT;
    int tid = threadIdx.x;
    #pragma unroll
    for (int s = 0; s < 12; ++s) {    // 64 rows x 48 chunks of 8 bf16
        int cc = tid + 256 * s;
        int r = cc / 48, ch = cc % 48;
        int row = m0 + r;
        if (mat == 3 && row > 4095) row = 4095;
        *reinterpret_cast<int4*>(&a_lds[r][ch * 8]) =
            *reinterpret_cast<const int4*>(A + (size_t)row * HID + ch * 8);
    }
    __syncthreads();
    int lane = tid & 63, w = tid >> 6;   // w == head h == n-quarter
    int c = lane & 15, g = lane >> 4;
    int h = w;
    const bf16* WTb = WT + (size_t)(96 * w) * HID;
    f32x4 acc[4][6] = {};
    for (int ks = 0; ks < 12; ++ks) {
        bf16x8 b0 = *reinterpret_cast<const bf16x8*>(WTb + (size_t)(c) * HID + 32 * ks + 8 * g);
        bf16x8 b1 = *reinterpret_cast<const bf16x8*>(WTb + (size_t)(16 + c) * HID + 32 * ks + 8 * g);
        bf16x8 b2 = *reinterpret_cast<const bf16x8*>(WTb + (size_t)(32 + c) * HID + 32 * ks + 8 * g);
        bf16x8 b3 = *reinterpret_cast<const bf16x8*>(WTb + (size_t)(48 + c) * HID + 32 * ks + 8 * g);
        bf16x8 b4 = *reinterpret_cast<const bf16x8*>(WTb + (size_t)(64 + c) * HID + 32 * ks + 8 * g);
        bf16x8 b5 = *reinterpret_cast<const bf16x8*>(WTb + (size_t)(80 + c) * HID + 32 * ks + 8 * g);
        #pragma unroll
        for (int i = 0; i < 4; ++i) {
            bf16x8 a = *reinterpret_cast<const bf16x8*>(&a_lds[16 * i + c][32 * ks + 8 * g]);
            acc[i][0] = mfma16(a, b0, acc[i][0]);
            acc[i][1] = mfma16(a, b1, acc[i][1]);
            acc[i][2] = mfma16(a, b2, acc[i][2]);
            acc[i][3] = mfma16(a, b3, acc[i][3]);
            acc[i][4] = mfma16(a, b4, acc[i][4]);
            acc[i][5] = mfma16(a, b5, acc[i][5]);
        }
    }
    if (mat == 0) {
        #pragma unroll
        for (int jt = 0; jt < 6; ++jt) {
            int n = 96 * h + 16 * jt + c;
            int d = 16 * jt + c;
            float bb = bq[n], bu = pbu[n], bvv = pbv[n];
            #pragma unroll
            for (int i = 0; i < 4; ++i) {
                #pragma unroll
                for (int j = 0; j < 4; ++j) {
                    int m = m0 + 16 * i + 4 * g + j;
                    int b_ = m >> 11, t = m & 2047;
                    size_t o = (((size_t)(b_ * NHEAD + h)) * TSEQ + t) * HD + d;
                    float q = acc[i][jt][j] + bb;
                    qu[o] = (bf16)((q + bu) * SC);
                    qv[o] = (bf16)((q + bvv) * SC);
                }
            }
        }
    } else if (mat == 1) {
        #pragma unroll
        for (int jt = 0; jt < 6; ++jt) {
            int n = 96 * h + 16 * jt + c;
            int d = 16 * jt + c;
            float bb = bk[n];
            #pragma unroll
            for (int i = 0; i < 4; ++i) {
                #pragma unroll
                for (int j = 0; j < 4; ++j) {
                    int m = m0 + 16 * i + 4 * g + j;
                    int b_ = m >> 11, t = m & 2047;
                    size_t o = (((size_t)(b_ * NHEAD + h)) * TSEQ + t) * HD + d;
                    kws[o] = (bf16)(acc[i][jt][j] + bb);
                }
            }
        }
    } else if (mat == 2) {
        #pragma unroll
        for (int jt = 0; jt < 6; ++jt) {
            int d = 16 * jt + c;
            float bb = bv[96 * h + 16 * jt + c];
            #pragma unroll
            for (int i = 0; i < 4; ++i) {
                int m = m0 + 16 * i + 4 * g;
                int b_ = m >> 11, t0 = m & 2047;
                size_t o = (((size_t)(b_ * NHEAD + h)) * HD + d) * TSEQ + t0;
                bf16x4 pk;
                #pragma unroll
                for (int j = 0; j < 4; ++j) pk[j] = (bf16)(acc[i][jt][j] + bb);
                *reinterpret_cast<bf16x4*>(vt + o) = pk;
            }
        }
    } else {
        #pragma unroll
        for (int jt = 0; jt < 6; ++jt) {
            int d = 16 * jt + c;
            #pragma unroll
            for (int i = 0; i < 4; ++i) {
                #pragma unroll
                for (int j = 0; j < 4; ++j) {
                    int m = m0 + 16 * i + 4 * g + j;
                    if (m < 4095) {
                        size_t o = ((size_t)h * 4096 + m) * HD + d;
                        pp[o] = (bf16)acc[i][jt][j];
                    }
                }
            }
        }
    }
}

// ---------------- fused rel-pos flash attention (KVBLK=128) ----------------
// r16 champion + K-from-L2: QK's K A-frags read directly from global (L2;
// per-XCD working set 3.8MB <= 4MB by the XCD-local decode). K has ZERO
// within-wave reuse, so LDS staging only bought 4x cross-wave reuse — the L2
// redundancy is free BW, and the saturated LDS pipe loses 288cyc/wave-iter.
// k_lds + K DMA deleted (LDS 46KB). V stays DMA-staged; win as r16.
// 256 threads, 2 blocks/CU. S^T = mfma(K,Qu): lane(c,g) reg(tk,j) holds
// S^T[k=16tk+4g+j][q=c].
__launch_bounds__(256, 2)
__global__ void k_attn(const bf16* __restrict__ qu, const bf16* __restrict__ qv,
                       const bf16* __restrict__ kws, const bf16* __restrict__ vt,
                       const bf16* __restrict__ pp, const int* __restrict__ mask,
                       bf16* __restrict__ out) {
    __shared__ bf16 vt_lds[96][128];      // V^T tile, XOR(ch^(r&7)) chunk layout
    __shared__ bf16 wp_lds[4][16][168];   // win (x-indexed quads) / P — time-phased

    int bid = blockIdx.x;
    int x = bid & 7, j5 = bid >> 3;
    int h = x & 3;
    int b_ = (x >> 2) * 4 + (j5 >> 5);
    int qb = j5 & 31;
    int bh = b_ * NHEAD + h;
    int q0 = qb * 64;

    int tid = threadIdx.x, lane = tid & 63, w = tid >> 6;
    int c = lane & 15, g = lane >> 4;
    const float L2E = 1.44269504089f;
    const int NB = 2032 - q0 - 16 * w;    // wave's win-band base (kt=0)

    // ---- kt-invariant V staging coordinates (named scalars) ----
    bf16* vt_flat = &vt_lds[0][0];
    int cc0 = tid, cc1 = tid + 256, cc2 = tid + 512;
    int cc3 = tid + 768, cc4 = tid + 1024, cc5 = tid + 1280;
    int vr0 = cc0 >> 4, vc0 = cc0 & 15;  int vO0 = vr0 * TSEQ + (vc0 ^ (vr0 & 7)) * 8;
    int vr1 = cc1 >> 4, vc1 = cc1 & 15;  int vO1 = vr1 * TSEQ + (vc1 ^ (vr1 & 7)) * 8;
    int vr2 = cc2 >> 4, vc2 = cc2 & 15;  int vO2 = vr2 * TSEQ + (vc2 ^ (vr2 & 7)) * 8;
    int vr3 = cc3 >> 4, vc3 = cc3 & 15;  int vO3 = vr3 * TSEQ + (vc3 ^ (vr3 & 7)) * 8;
    int vr4 = cc4 >> 4, vc4 = cc4 & 15;  int vO4 = vr4 * TSEQ + (vc4 ^ (vr4 & 7)) * 8;
    int vr5 = cc5 >> 4, vc5 = cc5 & 15;  int vO5 = vr5 * TSEQ + (vc5 ^ (vr5 & 7)) * 8;
    bf16* vL0 = vt_flat + (size_t)(64 * w + 0)    * 8;
    bf16* vL1 = vt_flat + (size_t)(64 * w + 256)  * 8;
    bf16* vL2 = vt_flat + (size_t)(64 * w + 512)  * 8;
    bf16* vL3 = vt_flat + (size_t)(64 * w + 768)  * 8;
    bf16* vL4 = vt_flat + (size_t)(64 * w + 1024) * 8;
    bf16* vL5 = vt_flat + (size_t)(64 * w + 1280) * 8;

    const bf16* kbP = kws + (size_t)bh * TSEQ * HD;
    const bf16* vbP = vt + (size_t)bh * HD * TSEQ;
    const bf16* pbP = pp + (size_t)h * 4096 * HD;
    const int*  mbP = mask + b_ * TSEQ;

    bf16x8 qu_f[3], qv_f[3];
    {
        size_t rowbase = ((size_t)bh * TSEQ + q0 + 16 * w + c) * HD + 8 * g;
        #pragma unroll
        for (int ds = 0; ds < 3; ++ds) {
            qu_f[ds] = *reinterpret_cast<const bf16x8*>(qu + rowbase + 32 * ds);
            qv_f[ds] = *reinterpret_cast<const bf16x8*>(qv + rowbase + 32 * ds);
        }
    }

    f32x4 acc_o[6] = {};
    float mrow = -3.0e38f, lrow = 0.f;
    f32x4 wc;          // win carry: tile8 of iter kt == tile0 of kt+1
    int   mk0, mk1;    // pipelined mask words for the CURRENT tile

    bf16* wp_row = &wp_lds[w][c][0];
    const int hc = (15 - c) >> 2;         // gather quad offset
    const int sh = ((15 - c) & 3) * 16;   // gather funnel-shift (bits)

    // ---- compute+spill a PAIR of win tiles (aligned bf16x4 stores) ----
    auto winpair = [&](int wb, int ta, int tb) {
        f32x4 wa = {}, wbv = {};
        const bf16* pa = pbP + (size_t)(wb + 16 * ta + c) * HD + 8 * g;
        const bf16* pb = pbP + (size_t)(wb + 16 * tb + c) * HD + 8 * g;
        __builtin_amdgcn_s_setprio(1);
        #pragma unroll
        for (int ds = 0; ds < 3; ++ds) {
            wa  = mfma16(*reinterpret_cast<const bf16x8*>(pa + 32 * ds), qv_f[ds], wa);
            wbv = mfma16(*reinterpret_cast<const bf16x8*>(pb + 32 * ds), qv_f[ds], wbv);
        }
        __builtin_amdgcn_s_setprio(0);
        bf16x4 qa, qb;
        #pragma unroll
        for (int j = 0; j < 4; ++j) { qa[j] = (bf16)wa[j]; qb[j] = (bf16)wbv[j]; }
        *reinterpret_cast<bf16x4*>(wp_row + 16 * ta + 4 * g) = qa;
        *reinterpret_cast<bf16x4*>(wp_row + 16 * tb + 4 * g) = qb;
        return wbv;
    };

    // ---- prologue: stage tile 0 (V DMA), mask, win[0] tiles 0..8 ----
    {
        GL2LDS(vbP + vO0, vL0); GL2LDS(vbP + vO1, vL1); GL2LDS(vbP + vO2, vL2);
        GL2LDS(vbP + vO3, vL3); GL2LDS(vbP + vO4, vL4); GL2LDS(vbP + vO5, vL5);
        mk0 = mbP[lane]; mk1 = mbP[64 + lane];

        {   // tile 0
            f32x4 w0 = {};
            const bf16* p0 = pbP + (size_t)(NB + c) * HD + 8 * g;
            #pragma unroll
            for (int ds = 0; ds < 3; ++ds)
                w0 = mfma16(*reinterpret_cast<const bf16x8*>(p0 + 32 * ds), qv_f[ds], w0);
            bf16x4 q0v;
            #pragma unroll
            for (int j = 0; j < 4; ++j) q0v[j] = (bf16)w0[j];
            *reinterpret_cast<bf16x4*>(wp_row + 4 * g) = q0v;
        }
        winpair(NB, 1, 2);
        winpair(NB, 3, 4);
        winpair(NB, 5, 6);
        wc = winpair(NB, 7, 8);
    }
    __syncthreads();  // drains vmcnt (V DMA) + lgkm (win spills)

    for (int kt = 0; kt < 16; ++kt) {
        int k0 = kt * 128;
        unsigned long long bm0 = __ballot(mk0 != 0);
        unsigned long long bm1 = __ballot(mk1 != 0);

        // ---- gather win[kt]: 2 aligned b64 + funnel shift per tile ----
        bf16x4 wv[8];
        #pragma unroll
        for (int tk = 0; tk < 8; ++tk) {
            int qd = 4 * tk + g + hc;
            u64 A8 = *reinterpret_cast<const u64*>(wp_row + 4 * qd);
            u64 B8 = *reinterpret_cast<const u64*>(wp_row + 4 * qd + 4);
            u64 o8 = sh ? ((A8 >> sh) | (B8 << (64 - sh))) : A8;
            *reinterpret_cast<u64*>(&wv[tk]) = o8;
        }

        // ---- content scores S^T: K A-frags DIRECT FROM L2; seeded with win
        f32x4 acc_s[8];
        #pragma unroll
        for (int tk = 0; tk < 8; ++tk)
            acc_s[tk] = f32x4{(float)wv[tk][0], (float)wv[tk][1],
                              (float)wv[tk][2], (float)wv[tk][3]};
        __builtin_amdgcn_s_setprio(1);
        #pragma unroll
        for (int ds = 0; ds < 3; ++ds) {
            #pragma unroll
            for (int tk = 0; tk < 8; ++tk) {
                bf16x8 a = *reinterpret_cast<const bf16x8*>(
                    kbP + (size_t)(k0 + 16 * tk + c) * HD + 32 * ds + 8 * g);
                acc_s[tk] = mfma16(a, qu_f[ds], acc_s[tk]);
            }
        }
        __builtin_amdgcn_s_setprio(0);

        // ---- mask + online softmax (per-lane row q=c) ----
        if ((bm0 & bm1) != ~0ull) {
            #pragma unroll
            for (int tk = 0; tk < 8; ++tk) {
                unsigned long long bb = (tk < 4) ? bm0 : bm1;
                int base = 16 * (tk & 3) + 4 * g;
                #pragma unroll
                for (int j = 0; j < 4; ++j)
                    if (!((bb >> (base + j)) & 1)) acc_s[tk][j] = -3.0e38f;
            }
        }
        float pm = acc_s[0][0];
        #pragma unroll
        for (int tk = 0; tk < 8; ++tk)
            #pragma unroll
            for (int j = 0; j < 4; ++j) pm = fmaxf(pm, acc_s[tk][j]);
        pm = fmaxf(pm, __shfl_xor(pm, 16));
        pm = fmaxf(pm, __shfl_xor(pm, 32));
        if (!__all(pm <= mrow + 8.0f)) {   // defer-max (THR=8)
            float mnew = fmaxf(mrow, pm);
            float alpha = exp2f((mrow - mnew) * L2E);
            mrow = mnew; lrow *= alpha;
            #pragma unroll
            for (int ot = 0; ot < 6; ++ot) acc_o[ot] *= alpha;
        }
        float rs = 0.f;
        #pragma unroll
        for (int tk = 0; tk < 8; ++tk)
            #pragma unroll
            for (int j = 0; j < 4; ++j) {
                float p = exp2f((acc_s[tk][j] - mrow) * L2E);
                acc_s[tk][j] = p; rs += p;
            }
        rs += __shfl_xor(rs, 16);
        rs += __shfl_xor(rs, 32);
        lrow += rs;

        // ---- P -> LDS (col-major [q][k], aligned b64) ----
        #pragma unroll
        for (int tk = 0; tk < 8; ++tk) {
            bf16x4 pk;
            #pragma unroll
            for (int j = 0; j < 4; ++j) pk[j] = (bf16)acc_s[tk][j];
            *reinterpret_cast<bf16x4*>(wp_row + 16 * tk + 4 * g) = pk;
        }
        LDS_HANDOFF();  // P spills -> PV B-frags (cross-lane, same wave)

        // ---- PV: O^T += V^T . P ----
        __builtin_amdgcn_s_setprio(1);
        #pragma unroll
        for (int ds = 0; ds < 4; ++ds) {
            bf16x8 pb_ = *reinterpret_cast<const bf16x8*>(wp_row + 32 * ds + 8 * g);
            #pragma unroll
            for (int ot = 0; ot < 6; ++ot) {
                int rr = 16 * ot + c;
                bf16x8 a = *reinterpret_cast<const bf16x8*>(
                    &vt_lds[rr][(((4 * ds + g) ^ (rr & 7)) * 8)]);
                acc_o[ot] = mfma16(a, pb_, acc_o[ot]);
            }
        }
        __builtin_amdgcn_s_setprio(0);

        if (kt < 15) {
            __syncthreads();  // barrier1: all waves done reading tile kt

            // ---- issue V DMA for tile kt+1 FIRST (latency hidden by win) ----
            int k0n = k0 + 128;
            const bf16* vb = vbP + k0n;
            GL2LDS(vb + vO0, vL0); GL2LDS(vb + vO1, vL1); GL2LDS(vb + vO2, vL2);
            GL2LDS(vb + vO3, vL3); GL2LDS(vb + vO4, vL4); GL2LDS(vb + vO5, vL5);
            mk0 = mbP[k0n + lane]; mk1 = mbP[k0n + 64 + lane];

            // ---- win[kt+1]: carry as tile0 (aligned), tiles 1..8 in pairs ----
            int wb = NB + 128 * (kt + 1);
            bf16x4 q0v;
            #pragma unroll
            for (int j = 0; j < 4; ++j) q0v[j] = (bf16)wc[j];
            *reinterpret_cast<bf16x4*>(wp_row + 4 * g) = q0v;
            winpair(wb, 1, 2);
            winpair(wb, 3, 4);
            winpair(wb, 5, 6);
            wc = winpair(wb, 7, 8);

            __syncthreads();  // barrier2: vmcnt mostly drained under win compute
        }
    }

    // ---- epilogue ----
    float inv = 1.0f / lrow;
    size_t m = (size_t)b_ * TSEQ + q0 + 16 * w + c;
    bf16* ob = out + m * HID + h * HD + 4 * g;
    #pragma unroll
    for (int ot = 0; ot < 6; ++ot) {
        bf16x4 pk;
        #pragma unroll
        for (int j = 0; j < 4; ++j) pk[j] = (bf16)(acc_o[ot][j] * inv);
        *reinterpret_cast<bf16x4*>(&ob[16 * ot]) = pk;
    }
}

// ---------------- output projection ----------------
__launch_bounds__(256, 2)
__global__ void k_oproj(const bf16* __restrict__ A, const bf16* __restrict__ WT,
                        const float* __restrict__ bias, float* __restrict__ out) {
    __shared__ bf16 wt_lds[96][392];
    int m0 = blockIdx.x * 64, n0 = blockIdx.y * 96;
    int tid = threadIdx.x;
    #pragma unroll
    for (int s = 0; s < 18; ++s) {
        int cc = tid + 256 * s;
        int r = cc / 48, ch = cc % 48;
        *reinterpret_cast<int4*>(&wt_lds[r][ch * 8]) =
            *reinterpret_cast<const int4*>(WT + (size_t)(n0 + r) * HID + ch * 8);
    }
    __syncthreads();
    int lane = tid & 63, w = tid >> 6;
    int c = lane & 15, g = lane >> 4;
    const bf16* Abase = A + (size_t)(m0 + 16 * w + c) * HID + 8 * g;
    f32x4 acc[6] = {};
    for (int ks = 0; ks < 12; ++ks) {
        bf16x8 a = *reinterpret_cast<const bf16x8*>(Abase + 32 * ks);
        #pragma unroll
        for (int jt = 0; jt < 6; ++jt) {
            bf16x8 b = *reinterpret_cast<const bf16x8*>(&wt_lds[16 * jt + c][32 * ks + 8 * g]);
            acc[jt] = mfma16(a, b, acc[jt]);
        }
    }
    int rbase = m0 + 16 * w + 4 * g;
    #pragma unroll
    for (int jt = 0; jt < 6; ++jt) {
        int n = n0 + 16 * jt + c;
        float bb = bias[n];
        #pragma unroll
        for (int j = 0; j < 4; ++j)
            out[(size_t)(rbase + j) * HID + n] = acc[jt][j] + bb;
    }
}

extern "C" void kernel_launch(void* const* d_in, const int* in_sizes, int n_in,
                              void* d_out, int out_size, void* d_ws, size_t ws_size,
                              hipStream_t stream) {
    const float* hs  = (const float*)d_in[0];
    const float* pe  = (const float*)d_in[1];
    const int*   msk = (const int*)d_in[2];
    const float* Wq  = (const float*)d_in[3];
    const float* bq  = (const float*)d_in[4];
    const float* Wk  = (const float*)d_in[5];
    const float* bk  = (const float*)d_in[6];
    const float* Wv  = (const float*)d_in[7];
    const float* bv  = (const float*)d_in[8];
    const float* Wo  = (const float*)d_in[9];
    const float* bo  = (const float*)d_in[10];
    const float* Wp  = (const float*)d_in[11];
    const float* pbu = (const float*)d_in[12];
    const float* pbv = (const float*)d_in[13];

    char* ws = (char*)d_ws;
    size_t off = 0;
    auto alloc = [&](size_t b) { char* p = ws + off; off += (b + 255) & ~(size_t)255; return p; };
    bf16* Xb  = (bf16*)alloc((size_t)16384 * HID * 2);
    bf16* Pb  = (bf16*)alloc((size_t)4096 * HID * 2);
    bf16* wqT = (bf16*)alloc((size_t)HID * HID * 2);
    bf16* wkT = (bf16*)alloc((size_t)HID * HID * 2);
    bf16* wvT = (bf16*)alloc((size_t)HID * HID * 2);
    bf16* woT = (bf16*)alloc((size_t)HID * HID * 2);
    bf16* wpT = (bf16*)alloc((size_t)HID * HID * 2);
    bf16* qu  = (bf16*)alloc((size_t)NBATCH * NHEAD * TSEQ * HD * 2);
    bf16* qv  = (bf16*)alloc((size_t)NBATCH * NHEAD * TSEQ * HD * 2);
    bf16* kws = (bf16*)alloc((size_t)NBATCH * NHEAD * TSEQ * HD * 2);
    bf16* vt  = (bf16*)alloc((size_t)NBATCH * NHEAD * TSEQ * HD * 2);
    bf16* pp  = (bf16*)alloc((size_t)NHEAD * 4096 * HD * 2 + 65536);  // +slack
    bf16* ao  = (bf16*)alloc((size_t)16384 * HID * 2);

    k_conv8<<<3072, 256, 0, stream>>>(hs, Xb, 786432);
    k_conv8<<<768, 256, 0, stream>>>(pe, Pb, 196560);
    k_convT5<<<dim3(576, 5), 256, 0, stream>>>(Wq, Wk, Wv, Wo, Wp,
                                               wqT, wkT, wvT, woT, wpT);
    k_proj<<<dim3(256, 4), 256, 0, stream>>>(Xb, Pb, wqT, wkT, wvT, wpT,
                                             bq, bk, bv, pbu, pbv,
                                             qu, qv, kws, vt, pp);
    k_attn<<<1024, 256, 0, stream>>>(qu, qv, kws, vt, pp, msk, ao);
    k_oproj<<<dim3(256, 4), 256, 0, stream>>>(ao, woT, bo, (float*)d_out);
}

// Round 18
// 258.870 us; speedup vs baseline: 1.3298x; 1.3298x over previous
//
#include <hip/hip_runtime.h>
#include <hip/hip_bf16.h>

#define TSEQ 2048
#define HID 384
#define NHEAD 4
#define HD 96
#define NBATCH 8

using bf16 = __bf16;
typedef bf16 bf16x8 __attribute__((ext_vector_type(8)));
typedef bf16 bf16x4 __attribute__((ext_vector_type(4)));
typedef float f32x4 __attribute__((ext_vector_type(4)));
typedef unsigned long long u64;

static __device__ __forceinline__ f32x4 mfma16(bf16x8 a, bf16x8 b, f32x4 c) {
    return __builtin_amdgcn_mfma_f32_16x16x32_bf16(a, b, c, 0, 0, 0);
}

// same-wave LDS handoff: wait ds ops without draining vmcnt; DS pinned both
// sides, VMEM/VALU/MFMA may cross (mask 0x7F = all but DS*).
#define LDS_HANDOFF()                                   \
    __builtin_amdgcn_sched_barrier(0x7F);               \
    asm volatile("s_waitcnt lgkmcnt(0)");               \
    __builtin_amdgcn_sched_barrier(0x7F)

// async global->LDS DMA, 16B per lane; LDS dest = wave-uniform base + lane*16.
#define GL2LDS(g, l) __builtin_amdgcn_global_load_lds(                        \
    (const __attribute__((address_space(1))) unsigned int*)(const void*)(g),  \
    (__attribute__((address_space(3))) unsigned int*)(void*)(l), 16, 0, 0)

// ---------------- conversion kernels ----------------
// merged: blocks [0,3072) convert hs (786432 x8), [3072,3840) convert pe
__global__ void k_conv8m(const float* __restrict__ hs, bf16* __restrict__ dhs,
                         const float* __restrict__ pe, bf16* __restrict__ dpe) {
    int blk = blockIdx.x;
    const float* src; bf16* dst; int t; int n8;
    if (blk < 3072) { src = hs; dst = dhs; t = blk * 256 + threadIdx.x; n8 = 786432; }
    else            { src = pe; dst = dpe; t = (blk - 3072) * 256 + threadIdx.x; n8 = 196560; }
    if (t >= n8) return;
    const float4* s4 = reinterpret_cast<const float4*>(src);
    float4 a = s4[2 * t], b = s4[2 * t + 1];
    bf16x8 o;
    o[0] = (bf16)a.x; o[1] = (bf16)a.y; o[2] = (bf16)a.z; o[3] = (bf16)a.w;
    o[4] = (bf16)b.x; o[5] = (bf16)b.y; o[6] = (bf16)b.z; o[7] = (bf16)b.w;
    *reinterpret_cast<bf16x8*>(dst + 8 * t) = o;
}

__global__ void k_convT5(const float* __restrict__ W0, const float* __restrict__ W1,
                         const float* __restrict__ W2, const float* __restrict__ W3,
                         const float* __restrict__ W4,
                         bf16* __restrict__ T0, bf16* __restrict__ T1,
                         bf16* __restrict__ T2, bf16* __restrict__ T3,
                         bf16* __restrict__ T4) {
    int t = blockIdx.x * 256 + threadIdx.x;  // T[n][k] = W[k][n]
    int which = blockIdx.y;
    const float* W = (which == 0) ? W0 : (which == 1) ? W1 : (which == 2) ? W2
                     : (which == 3) ? W3 : W4;
    bf16* T = (which == 0) ? T0 : (which == 1) ? T1 : (which == 2) ? T2
              : (which == 3) ? T3 : T4;
    int n = t / HID, k = t % HID;
    T[t] = (bf16)W[(size_t)k * HID + n];
}

// ---------------- projection GEMM (Q,K,V,pos) ----------------
__launch_bounds__(256, 2)
__global__ void k_proj(const bf16* __restrict__ X, const bf16* __restrict__ P,
                       const bf16* __restrict__ wqT, const bf16* __restrict__ wkT,
                       const bf16* __restrict__ wvT, const bf16* __restrict__ wpT,
                       const float* __restrict__ bq, const float* __restrict__ bk,
                       const float* __restrict__ bv,
                       const float* __restrict__ pbu, const float* __restrict__ pbv,
                       bf16* __restrict__ qu, bf16* __restrict__ qv,
                       bf16* __restrict__ kws, bf16* __restrict__ vt,
                       bf16* __restrict__ pp) {
    __shared__ bf16 wt_lds[96][392];
    const float SC = 0.10206207262f;  // 1/sqrt(96) folded into q
    int mat = blockIdx.z;             // 0=Q 1=K 2=V 3=POS
    int m0 = blockIdx.x * 64;
    if (mat == 3 && m0 >= 4095) return;
    int n0 = blockIdx.y * 96;
    const bf16* A  = (mat == 3) ? P : X;
    const bf16* WT = (mat == 0) ? wqT : (mat == 1) ? wkT : (mat == 2) ? wvT : wpT;
    int tid = threadIdx.x;
    #pragma unroll
    for (int s = 0; s < 18; ++s) {
        int cc = tid + 256 * s;
        int r = cc / 48, ch = cc % 48;
        *reinterpret_cast<int4*>(&wt_lds[r][ch * 8]) =
            *reinterpret_cast<const int4*>(WT + (size_t)(n0 + r) * HID + ch * 8);
    }
    __syncthreads();
    int lane = tid & 63, w = tid >> 6;
    int c = lane & 15, g = lane >> 4;
    int arow = m0 + 16 * w + c;
    if (mat == 3 && arow > 4095) arow = 4095;
    const bf16* Abase = A + (size_t)arow * HID + 8 * g;
    f32x4 acc[6] = {};
    for (int ks = 0; ks < 12; ++ks) {
        bf16x8 a = *reinterpret_cast<const bf16x8*>(Abase + 32 * ks);
        #pragma unroll
        for (int jt = 0; jt < 6; ++jt) {
            bf16x8 b = *reinterpret_cast<const bf16x8*>(&wt_lds[16 * jt + c][32 * ks + 8 * g]);
            acc[jt] = mfma16(a, b, acc[jt]);
        }
    }
    int h = blockIdx.y;
    int rbase = m0 + 16 * w + 4 * g;
    if (mat == 0) {
        #pragma unroll
        for (int jt = 0; jt < 6; ++jt) {
            int n = n0 + 16 * jt + c;
            int d = 16 * jt + c;
            float bb = bq[n], bu = pbu[n], bvv = pbv[n];
            #pragma unroll
            for (int j = 0; j < 4; ++j) {
                int m = rbase + j;
                int b_ = m >> 11, t = m & 2047;
                size_t o = (((size_t)(b_ * NHEAD + h)) * TSEQ + t) * HD + d;
                float q = acc[jt][j] + bb;
                qu[o] = (bf16)((q + bu) * SC);
                qv[o] = (bf16)((q + bvv) * SC);
            }
        }
    } else if (mat == 1) {
        #pragma unroll
        for (int jt = 0; jt < 6; ++jt) {
            int n = n0 + 16 * jt + c;
            int d = 16 * jt + c;
            float bb = bk[n];
            #pragma unroll
            for (int j = 0; j < 4; ++j) {
                int m = rbase + j;
                int b_ = m >> 11, t = m & 2047;
                size_t o = (((size_t)(b_ * NHEAD + h)) * TSEQ + t) * HD + d;
                kws[o] = (bf16)(acc[jt][j] + bb);
            }
        }
    } else if (mat == 2) {
        #pragma unroll
        for (int jt = 0; jt < 6; ++jt) {
            int d = 16 * jt + c;
            float bb = bv[n0 + 16 * jt + c];
            int m = rbase;
            int b_ = m >> 11, t0 = m & 2047;
            size_t o = (((size_t)(b_ * NHEAD + h)) * HD + d) * TSEQ + t0;
            bf16x4 pk;
            #pragma unroll
            for (int j = 0; j < 4; ++j) pk[j] = (bf16)(acc[jt][j] + bb);
            *reinterpret_cast<bf16x4*>(vt + o) = pk;
        }
    } else {
        #pragma unroll
        for (int jt = 0; jt < 6; ++jt) {
            int d = 16 * jt + c;
            #pragma unroll
            for (int j = 0; j < 4; ++j) {
                int m = rbase + j;
                if (m < 4095) {
                    size_t o = ((size_t)h * 4096 + m) * HD + d;
                    pp[o] = (bf16)acc[jt][j];
                }
            }
        }
    }
}

// ---------------- fused rel-pos flash attention (KVBLK=128) ----------------
// r16 champion restored (r17 lesson: operands consumed immediately by MFMA
// must come from LDS — K-from-L2 exposed 24 serial ~200cy loads, -28%).
// K tile [128][104] padded (GL2LDS 13-chunk rows, chunk12=pad); V^T XOR'd;
// win x-indexed quad spill + funnel-shift gather; win between the staging
// barriers covers the DMA drain; acc_s seeded from win gather.
// 256 threads, 2 blocks/CU (LDS 71KB, ~170 combined regs, no spill).
// S^T = mfma(K,Qu): lane(c,g) reg(tk,j) holds S^T[k=16tk+4g+j][q=c].
__launch_bounds__(256, 2)
__global__ void k_attn(const bf16* __restrict__ qu, const bf16* __restrict__ qv,
                       const bf16* __restrict__ kws, const bf16* __restrict__ vt,
                       const bf16* __restrict__ pp, const int* __restrict__ mask,
                       bf16* __restrict__ out) {
    __shared__ bf16 k_lds[128][104];      // K tile, padded rows (2-way banks)
    __shared__ bf16 vt_lds[96][128];      // V^T tile, XOR(ch^(r&7)) chunk layout
    __shared__ bf16 wp_lds[4][16][168];   // win (x-indexed quads) / P — time-phased

    int bid = blockIdx.x;
    int x = bid & 7, j5 = bid >> 3;
    int h = x & 3;
    int b_ = (x >> 2) * 4 + (j5 >> 5);
    int qb = j5 & 31;
    int bh = b_ * NHEAD + h;
    int q0 = qb * 64;

    int tid = threadIdx.x, lane = tid & 63, w = tid >> 6;
    int c = lane & 15, g = lane >> 4;
    const float L2E = 1.44269504089f;
    const int NB = 2032 - q0 - 16 * w;    // wave's win-band base (kt=0)

    // ---- kt-invariant staging coordinates (named scalars) ----
    bf16* k_flat = &k_lds[0][0];
    bf16* vt_flat = &vt_lds[0][0];
    int cc0 = tid, cc1 = tid + 256, cc2 = tid + 512, cc3 = tid + 768;
    int cc4 = tid + 1024, cc5 = tid + 1280, cc6 = tid + 1536;
    int kr0 = cc0 / 13, kc0 = cc0 % 13;  int kO0 = kr0 * HD + (kc0 == 12 ? 0 : kc0 * 8);
    int kr1 = cc1 / 13, kc1 = cc1 % 13;  int kO1 = kr1 * HD + (kc1 == 12 ? 0 : kc1 * 8);
    int kr2 = cc2 / 13, kc2 = cc2 % 13;  int kO2 = kr2 * HD + (kc2 == 12 ? 0 : kc2 * 8);
    int kr3 = cc3 / 13, kc3 = cc3 % 13;  int kO3 = kr3 * HD + (kc3 == 12 ? 0 : kc3 * 8);
    int kr4 = cc4 / 13, kc4 = cc4 % 13;  int kO4 = kr4 * HD + (kc4 == 12 ? 0 : kc4 * 8);
    int kr5 = cc5 / 13, kc5 = cc5 % 13;  int kO5 = kr5 * HD + (kc5 == 12 ? 0 : kc5 * 8);
    int kr6 = cc6 / 13, kc6 = cc6 % 13;  int kO6 = kr6 * HD + (kc6 == 12 ? 0 : kc6 * 8);
    bf16* kL0 = k_flat + (size_t)(64 * w + 0)    * 8;
    bf16* kL1 = k_flat + (size_t)(64 * w + 256)  * 8;
    bf16* kL2 = k_flat + (size_t)(64 * w + 512)  * 8;
    bf16* kL3 = k_flat + (size_t)(64 * w + 768)  * 8;
    bf16* kL4 = k_flat + (size_t)(64 * w + 1024) * 8;
    bf16* kL5 = k_flat + (size_t)(64 * w + 1280) * 8;
    bf16* kL6 = k_flat + (size_t)(64 * w + 1536) * 8;
    bool kAct6 = (w < 2);                 // cc6 < 1664 wave-uniform
    int vr0 = cc0 >> 4, vc0 = cc0 & 15;  int vO0 = vr0 * TSEQ + (vc0 ^ (vr0 & 7)) * 8;
    int vr1 = cc1 >> 4, vc1 = cc1 & 15;  int vO1 = vr1 * TSEQ + (vc1 ^ (vr1 & 7)) * 8;
    int vr2 = cc2 >> 4, vc2 = cc2 & 15;  int vO2 = vr2 * TSEQ + (vc2 ^ (vr2 & 7)) * 8;
    int vr3 = cc3 >> 4, vc3 = cc3 & 15;  int vO3 = vr3 * TSEQ + (vc3 ^ (vr3 & 7)) * 8;
    int vr4 = cc4 >> 4, vc4 = cc4 & 15;  int vO4 = vr4 * TSEQ + (vc4 ^ (vr4 & 7)) * 8;
    int vr5 = cc5 >> 4, vc5 = cc5 & 15;  int vO5 = vr5 * TSEQ + (vc5 ^ (vr5 & 7)) * 8;
    bf16* vL0 = vt_flat + (size_t)(64 * w + 0)    * 8;
    bf16* vL1 = vt_flat + (size_t)(64 * w + 256)  * 8;
    bf16* vL2 = vt_flat + (size_t)(64 * w + 512)  * 8;
    bf16* vL3 = vt_flat + (size_t)(64 * w + 768)  * 8;
    bf16* vL4 = vt_flat + (size_t)(64 * w + 1024) * 8;
    bf16* vL5 = vt_flat + (size_t)(64 * w + 1280) * 8;

    const bf16* kbP = kws + (size_t)bh * TSEQ * HD;
    const bf16* vbP = vt + (size_t)bh * HD * TSEQ;
    const bf16* pbP = pp + (size_t)h * 4096 * HD;
    const int*  mbP = mask + b_ * TSEQ;

    bf16x8 qu_f[3], qv_f[3];
    {
        size_t rowbase = ((size_t)bh * TSEQ + q0 + 16 * w + c) * HD + 8 * g;
        #pragma unroll
        for (int ds = 0; ds < 3; ++ds) {
            qu_f[ds] = *reinterpret_cast<const bf16x8*>(qu + rowbase + 32 * ds);
            qv_f[ds] = *reinterpret_cast<const bf16x8*>(qv + rowbase + 32 * ds);
        }
    }

    f32x4 acc_o[6] = {};
    float mrow = -3.0e38f, lrow = 0.f;
    f32x4 wc;          // win carry: tile8 of iter kt == tile0 of kt+1
    int   mk0, mk1;    // pipelined mask words for the CURRENT tile

    bf16* wp_row = &wp_lds[w][c][0];
    const int hc = (15 - c) >> 2;         // gather quad offset
    const int sh = ((15 - c) & 3) * 16;   // gather funnel-shift (bits)

    // ---- compute+spill a PAIR of win tiles (aligned bf16x4 stores) ----
    auto winpair = [&](int wb, int ta, int tb) {
        f32x4 wa = {}, wbv = {};
        const bf16* pa = pbP + (size_t)(wb + 16 * ta + c) * HD + 8 * g;
        const bf16* pb = pbP + (size_t)(wb + 16 * tb + c) * HD + 8 * g;
        __builtin_amdgcn_s_setprio(1);
        #pragma unroll
        for (int ds = 0; ds < 3; ++ds) {
            wa  = mfma16(*reinterpret_cast<const bf16x8*>(pa + 32 * ds), qv_f[ds], wa);
            wbv = mfma16(*reinterpret_cast<const bf16x8*>(pb + 32 * ds), qv_f[ds], wbv);
        }
        __builtin_amdgcn_s_setprio(0);
        bf16x4 qa, qb;
        #pragma unroll
        for (int j = 0; j < 4; ++j) { qa[j] = (bf16)wa[j]; qb[j] = (bf16)wbv[j]; }
        *reinterpret_cast<bf16x4*>(wp_row + 16 * ta + 4 * g) = qa;
        *reinterpret_cast<bf16x4*>(wp_row + 16 * tb + 4 * g) = qb;
        return wbv;
    };

    // ---- prologue: stage tile 0 (K+V DMA), mask, win[0] tiles 0..8 ----
    {
        GL2LDS(kbP + kO0, kL0); GL2LDS(kbP + kO1, kL1); GL2LDS(kbP + kO2, kL2);
        GL2LDS(kbP + kO3, kL3); GL2LDS(kbP + kO4, kL4); GL2LDS(kbP + kO5, kL5);
        if (kAct6) GL2LDS(kbP + kO6, kL6);
        GL2LDS(vbP + vO0, vL0); GL2LDS(vbP + vO1, vL1); GL2LDS(vbP + vO2, vL2);
        GL2LDS(vbP + vO3, vL3); GL2LDS(vbP + vO4, vL4); GL2LDS(vbP + vO5, vL5);
        mk0 = mbP[lane]; mk1 = mbP[64 + lane];

        {   // tile 0
            f32x4 w0 = {};
            const bf16* p0 = pbP + (size_t)(NB + c) * HD + 8 * g;
            #pragma unroll
            for (int ds = 0; ds < 3; ++ds)
                w0 = mfma16(*reinterpret_cast<const bf16x8*>(p0 + 32 * ds), qv_f[ds], w0);
            bf16x4 q0v;
            #pragma unroll
            for (int j = 0; j < 4; ++j) q0v[j] = (bf16)w0[j];
            *reinterpret_cast<bf16x4*>(wp_row + 4 * g) = q0v;
        }
        winpair(NB, 1, 2);
        winpair(NB, 3, 4);
        winpair(NB, 5, 6);
        wc = winpair(NB, 7, 8);
    }
    __syncthreads();  // drains vmcnt (K/V DMA) + lgkm (win spills)

    for (int kt = 0; kt < 16; ++kt) {
        unsigned long long bm0 = __ballot(mk0 != 0);
        unsigned long long bm1 = __ballot(mk1 != 0);

        // ---- gather win[kt]: 2 aligned b64 + funnel shift per tile ----
        bf16x4 wv[8];
        #pragma unroll
        for (int tk = 0; tk < 8; ++tk) {
            int qd = 4 * tk + g + hc;
            u64 A8 = *reinterpret_cast<const u64*>(wp_row + 4 * qd);
            u64 B8 = *reinterpret_cast<const u64*>(wp_row + 4 * qd + 4);
            u64 o8 = sh ? ((A8 >> sh) | (B8 << (64 - sh))) : A8;
            *reinterpret_cast<u64*>(&wv[tk]) = o8;
        }

        // ---- content scores S^T: acc_s seeded with win (MFMA adds for free)
        f32x4 acc_s[8];
        #pragma unroll
        for (int tk = 0; tk < 8; ++tk)
            acc_s[tk] = f32x4{(float)wv[tk][0], (float)wv[tk][1],
                              (float)wv[tk][2], (float)wv[tk][3]};
        __builtin_amdgcn_s_setprio(1);
        #pragma unroll
        for (int ds = 0; ds < 3; ++ds) {
            #pragma unroll
            for (int tk = 0; tk < 8; ++tk) {
                bf16x8 a = *reinterpret_cast<const bf16x8*>(
                    &k_lds[16 * tk + c][32 * ds + 8 * g]);
                acc_s[tk] = mfma16(a, qu_f[ds], acc_s[tk]);
            }
        }
        __builtin_amdgcn_s_setprio(0);

        // ---- mask + online softmax (per-lane row q=c) ----
        if ((bm0 & bm1) != ~0ull) {
            #pragma unroll
            for (int tk = 0; tk < 8; ++tk) {
                unsigned long long bb = (tk < 4) ? bm0 : bm1;
                int base = 16 * (tk & 3) + 4 * g;
                #pragma unroll
                for (int j = 0; j < 4; ++j)
                    if (!((bb >> (base + j)) & 1)) acc_s[tk][j] = -3.0e38f;
            }
        }
        float pm = acc_s[0][0];
        #pragma unroll
        for (int tk = 0; tk < 8; ++tk)
            #pragma unroll
            for (int j = 0; j < 4; ++j) pm = fmaxf(pm, acc_s[tk][j]);
        pm = fmaxf(pm, __shfl_xor(pm, 16));
        pm = fmaxf(pm, __shfl_xor(pm, 32));
        if (!__all(pm <= mrow + 8.0f)) {   // defer-max (THR=8)
            float mnew = fmaxf(mrow, pm);
            float alpha = exp2f((mrow - mnew) * L2E);
            mrow = mnew; lrow *= alpha;
            #pragma unroll
            for (int ot = 0; ot < 6; ++ot) acc_o[ot] *= alpha;
        }
        float rs = 0.f;
        #pragma unroll
        for (int tk = 0; tk < 8; ++tk)
            #pragma unroll
            for (int j = 0; j < 4; ++j) {
                float p = exp2f((acc_s[tk][j] - mrow) * L2E);
                acc_s[tk][j] = p; rs += p;
            }
        rs += __shfl_xor(rs, 16);
        rs += __shfl_xor(rs, 32);
        lrow += rs;

        // ---- P -> LDS (col-major [q][k], aligned b64) ----
        #pragma unroll
        for (int tk = 0; tk < 8; ++tk) {
            bf16x4 pk;
            #pragma unroll
            for (int j = 0; j < 4; ++j) pk[j] = (bf16)acc_s[tk][j];
            *reinterpret_cast<bf16x4*>(wp_row + 16 * tk + 4 * g) = pk;
        }
        LDS_HANDOFF();  // P spills -> PV B-frags (cross-lane, same wave)

        // ---- PV: O^T += V^T . P ----
        __builtin_amdgcn_s_setprio(1);
        #pragma unroll
        for (int ds = 0; ds < 4; ++ds) {
            bf16x8 pb_ = *reinterpret_cast<const bf16x8*>(wp_row + 32 * ds + 8 * g);
            #pragma unroll
            for (int ot = 0; ot < 6; ++ot) {
                int rr = 16 * ot + c;
                bf16x8 a = *reinterpret_cast<const bf16x8*>(
                    &vt_lds[rr][(((4 * ds + g) ^ (rr & 7)) * 8)]);
                acc_o[ot] = mfma16(a, pb_, acc_o[ot]);
            }
        }
        __builtin_amdgcn_s_setprio(0);

        if (kt < 15) {
            __syncthreads();  // barrier1: all waves done reading tile kt

            // ---- issue K+V DMA for tile kt+1 FIRST (latency hidden by win) ----
            int k0n = (kt + 1) * 128;
            const bf16* kb = kbP + (size_t)k0n * HD;
            const bf16* vb = vbP + k0n;
            GL2LDS(kb + kO0, kL0); GL2LDS(kb + kO1, kL1); GL2LDS(kb + kO2, kL2);
            GL2LDS(kb + kO3, kL3); GL2LDS(kb + kO4, kL4); GL2LDS(kb + kO5, kL5);
            if (kAct6) GL2LDS(kb + kO6, kL6);
            GL2LDS(vb + vO0, vL0); GL2LDS(vb + vO1, vL1); GL2LDS(vb + vO2, vL2);
            GL2LDS(vb + vO3, vL3); GL2LDS(vb + vO4, vL4); GL2LDS(vb + vO5, vL5);
            mk0 = mbP[k0n + lane]; mk1 = mbP[k0n + 64 + lane];

            // ---- win[kt+1]: carry as tile0 (aligned), tiles 1..8 in pairs ----
            int wb = NB + 128 * (kt + 1);
            bf16x4 q0v;
            #pragma unroll
            for (int j = 0; j < 4; ++j) q0v[j] = (bf16)wc[j];
            *reinterpret_cast<bf16x4*>(wp_row + 4 * g) = q0v;
            winpair(wb, 1, 2);
            winpair(wb, 3, 4);
            winpair(wb, 5, 6);
            wc = winpair(wb, 7, 8);

            __syncthreads();  // barrier2: vmcnt mostly drained under win compute
        }
    }

    // ---- epilogue ----
    float inv = 1.0f / lrow;
    size_t m = (size_t)b_ * TSEQ + q0 + 16 * w + c;
    bf16* ob = out + m * HID + h * HD + 4 * g;
    #pragma unroll
    for (int ot = 0; ot < 6; ++ot) {
        bf16x4 pk;
        #pragma unroll
        for (int j = 0; j < 4; ++j) pk[j] = (bf16)(acc_o[ot][j] * inv);
        *reinterpret_cast<bf16x4*>(&ob[16 * ot]) = pk;
    }
}

// ---------------- output projection ----------------
__launch_bounds__(256, 2)
__global__ void k_oproj(const bf16* __restrict__ A, const bf16* __restrict__ WT,
                        const float* __restrict__ bias, float* __restrict__ out) {
    __shared__ bf16 wt_lds[96][392];
    int m0 = blockIdx.x * 64, n0 = blockIdx.y * 96;
    int tid = threadIdx.x;
    #pragma unroll
    for (int s = 0; s < 18; ++s) {
        int cc = tid + 256 * s;
        int r = cc / 48, ch = cc % 48;
        *reinterpret_cast<int4*>(&wt_lds[r][ch * 8]) =
            *reinterpret_cast<const int4*>(WT + (size_t)(n0 + r) * HID + ch * 8);
    }
    __syncthreads();
    int lane = tid & 63, w = tid >> 6;
    int c = lane & 15, g = lane >> 4;
    const bf16* Abase = A + (size_t)(m0 + 16 * w + c) * HID + 8 * g;
    f32x4 acc[6] = {};
    for (int ks = 0; ks < 12; ++ks) {
        bf16x8 a = *reinterpret_cast<const bf16x8*>(Abase + 32 * ks);
        #pragma unroll
        for (int jt = 0; jt < 6; ++jt) {
            bf16x8 b = *reinterpret_cast<const bf16x8*>(&wt_lds[16 * jt + c][32 * ks + 8 * g]);
            acc[jt] = mfma16(a, b, acc[jt]);
        }
    }
    int rbase = m0 + 16 * w + 4 * g;
    #pragma unroll
    for (int jt = 0; jt < 6; ++jt) {
        int n = n0 + 16 * jt + c;
        float bb = bias[n];
        #pragma unroll
        for (int j = 0; j < 4; ++j)
            out[(size_t)(rbase + j) * HID + n] = acc[jt][j] + bb;
    }
}

extern "C" void kernel_launch(void* const* d_in, const int* in_sizes, int n_in,
                              void* d_out, int out_size, void* d_ws, size_t ws_size,
                              hipStream_t stream) {
    const float* hs  = (const float*)d_in[0];
    const float* pe  = (const float*)d_in[1];
    const int*   msk = (const int*)d_in[2];
    const float* Wq  = (const float*)d_in[3];
    const float* bq  = (const float*)d_in[4];
    const float* Wk  = (const float*)d_in[5];
    const float* bk  = (const float*)d_in[6];
    const float* Wv  = (const float*)d_in[7];
    const float* bv  = (const float*)d_in[8];
    const float* Wo  = (const float*)d_in[9];
    const float* bo  = (const float*)d_in[10];
    const float* Wp  = (const float*)d_in[11];
    const float* pbu = (const float*)d_in[12];
    const float* pbv = (const float*)d_in[13];

    char* ws = (char*)d_ws;
    size_t off = 0;
    auto alloc = [&](size_t b) { char* p = ws + off; off += (b + 255) & ~(size_t)255; return p; };
    bf16* Xb  = (bf16*)alloc((size_t)16384 * HID * 2);
    bf16* Pb  = (bf16*)alloc((size_t)4096 * HID * 2);
    bf16* wqT = (bf16*)alloc((size_t)HID * HID * 2);
    bf16* wkT = (bf16*)alloc((size_t)HID * HID * 2);
    bf16* wvT = (bf16*)alloc((size_t)HID * HID * 2);
    bf16* woT = (bf16*)alloc((size_t)HID * HID * 2);
    bf16* wpT = (bf16*)alloc((size_t)HID * HID * 2);
    bf16* qu  = (bf16*)alloc((size_t)NBATCH * NHEAD * TSEQ * HD * 2);
    bf16* qv  = (bf16*)alloc((size_t)NBATCH * NHEAD * TSEQ * HD * 2);
    bf16* kws = (bf16*)alloc((size_t)NBATCH * NHEAD * TSEQ * HD * 2);
    bf16* vt  = (bf16*)alloc((size_t)NBATCH * NHEAD * TSEQ * HD * 2);
    bf16* pp  = (bf16*)alloc((size_t)NHEAD * 4096 * HD * 2 + 65536);  // +slack
    bf16* ao  = (bf16*)alloc((size_t)16384 * HID * 2);

    k_conv8m<<<3840, 256, 0, stream>>>(hs, Xb, pe, Pb);
    k_convT5<<<dim3(576, 5), 256, 0, stream>>>(Wq, Wk, Wv, Wo, Wp,
                                               wqT, wkT, wvT, woT, wpT);
    k_proj<<<dim3(256, 4, 4), 256, 0, stream>>>(Xb, Pb, wqT, wkT, wvT, wpT,
                                                bq, bk, bv, pbu, pbv,
                                                qu, qv, kws, vt, pp);
    k_attn<<<1024, 256, 0, stream>>>(qu, qv, kws, vt, pp, msk, ao);
    k_oproj<<<dim3(256, 4), 256, 0, stream>>>(ao, woT, bo, (float*)d_out);
}

// Round 19
// 256.035 us; speedup vs baseline: 1.3445x; 1.0111x over previous
//
#include <hip/hip_runtime.h>
#include <hip/hip_bf16.h>

#define TSEQ 2048
#define HID 384
#define NHEAD 4
#define HD 96
#define NBATCH 8

using bf16 = __bf16;
typedef bf16 bf16x8 __attribute__((ext_vector_type(8)));
typedef bf16 bf16x4 __attribute__((ext_vector_type(4)));
typedef float f32x4 __attribute__((ext_vector_type(4)));
typedef unsigned long long u64;

static __device__ __forceinline__ f32x4 mfma16(bf16x8 a, bf16x8 b, f32x4 c) {
    return __builtin_amdgcn_mfma_f32_16x16x32_bf16(a, b, c, 0, 0, 0);
}

// same-wave LDS handoff: wait ds ops without draining vmcnt; DS pinned both
// sides, VMEM/VALU/MFMA may cross (mask 0x7F = all but DS*).
#define LDS_HANDOFF()                                   \
    __builtin_amdgcn_sched_barrier(0x7F);               \
    asm volatile("s_waitcnt lgkmcnt(0)");               \
    __builtin_amdgcn_sched_barrier(0x7F)

// async global->LDS DMA, 16B per lane; LDS dest = wave-uniform base + lane*16.
#define GL2LDS(g, l) __builtin_amdgcn_global_load_lds(                        \
    (const __attribute__((address_space(1))) unsigned int*)(const void*)(g),  \
    (__attribute__((address_space(3))) unsigned int*)(void*)(l), 16, 0, 0)

// ---------------- conversion kernels ----------------
// merged: blocks [0,3072) convert hs (786432 x8), [3072,3840) convert pe
__global__ void k_conv8m(const float* __restrict__ hs, bf16* __restrict__ dhs,
                         const float* __restrict__ pe, bf16* __restrict__ dpe) {
    int blk = blockIdx.x;
    const float* src; bf16* dst; int t; int n8;
    if (blk < 3072) { src = hs; dst = dhs; t = blk * 256 + threadIdx.x; n8 = 786432; }
    else            { src = pe; dst = dpe; t = (blk - 3072) * 256 + threadIdx.x; n8 = 196560; }
    if (t >= n8) return;
    const float4* s4 = reinterpret_cast<const float4*>(src);
    float4 a = s4[2 * t], b = s4[2 * t + 1];
    bf16x8 o;
    o[0] = (bf16)a.x; o[1] = (bf16)a.y; o[2] = (bf16)a.z; o[3] = (bf16)a.w;
    o[4] = (bf16)b.x; o[5] = (bf16)b.y; o[6] = (bf16)b.z; o[7] = (bf16)b.w;
    *reinterpret_cast<bf16x8*>(dst + 8 * t) = o;
}

__global__ void k_convT5(const float* __restrict__ W0, const float* __restrict__ W1,
                         const float* __restrict__ W2, const float* __restrict__ W3,
                         const float* __restrict__ W4,
                         bf16* __restrict__ T0, bf16* __restrict__ T1,
                         bf16* __restrict__ T2, bf16* __restrict__ T3,
                         bf16* __restrict__ T4) {
    int t = blockIdx.x * 256 + threadIdx.x;  // T[n][k] = W[k][n]
    int which = blockIdx.y;
    const float* W = (which == 0) ? W0 : (which == 1) ? W1 : (which == 2) ? W2
                     : (which == 3) ? W3 : W4;
    bf16* T = (which == 0) ? T0 : (which == 1) ? T1 : (which == 2) ? T2
              : (which == 3) ? T3 : T4;
    int n = t / HID, k = t % HID;
    T[t] = (bf16)W[(size_t)k * HID + n];
}

// ---------------- projection GEMM (Q,K,V,pos) ----------------
__launch_bounds__(256, 2)
__global__ void k_proj(const bf16* __restrict__ X, const bf16* __restrict__ P,
                       const bf16* __restrict__ wqT, const bf16* __restrict__ wkT,
                       const bf16* __restrict__ wvT, const bf16* __restrict__ wpT,
                       const float* __restrict__ bq, const float* __restrict__ bk,
                       const float* __restrict__ bv,
                       const float* __restrict__ pbu, const float* __restrict__ pbv,
                       bf16* __restrict__ qu, bf16* __restrict__ qv,
                       bf16* __restrict__ kws, bf16* __restrict__ vt,
                       bf16* __restrict__ pp) {
    __shared__ bf16 wt_lds[96][392];
    // 1/sqrt(96) * log2(e) folded into q: softmax then uses exp2 directly
    // (saves 32 v_mul per wave-iter in k_attn; P values numerically identical)
    const float SC = 0.14724450f;
    int mat = blockIdx.z;             // 0=Q 1=K 2=V 3=POS
    int m0 = blockIdx.x * 64;
    if (mat == 3 && m0 >= 4095) return;
    int n0 = blockIdx.y * 96;
    const bf16* A  = (mat == 3) ? P : X;
    const bf16* WT = (mat == 0) ? wqT : (mat == 1) ? wkT : (mat == 2) ? wvT : wpT;
    int tid = threadIdx.x;
    #pragma unroll
    for (int s = 0; s < 18; ++s) {
        int cc = tid + 256 * s;
        int r = cc / 48, ch = cc % 48;
        *reinterpret_cast<int4*>(&wt_lds[r][ch * 8]) =
            *reinterpret_cast<const int4*>(WT + (size_t)(n0 + r) * HID + ch * 8);
    }
    __syncthreads();
    int lane = tid & 63, w = tid >> 6;
    int c = lane & 15, g = lane >> 4;
    int arow = m0 + 16 * w + c;
    if (mat == 3 && arow > 4095) arow = 4095;
    const bf16* Abase = A + (size_t)arow * HID + 8 * g;
    f32x4 acc[6] = {};
    for (int ks = 0; ks < 12; ++ks) {
        bf16x8 a = *reinterpret_cast<const bf16x8*>(Abase + 32 * ks);
        #pragma unroll
        for (int jt = 0; jt < 6; ++jt) {
            bf16x8 b = *reinterpret_cast<const bf16x8*>(&wt_lds[16 * jt + c][32 * ks + 8 * g]);
            acc[jt] = mfma16(a, b, acc[jt]);
        }
    }
    int h = blockIdx.y;
    int rbase = m0 + 16 * w + 4 * g;
    if (mat == 0) {
        #pragma unroll
        for (int jt = 0; jt < 6; ++jt) {
            int n = n0 + 16 * jt + c;
            int d = 16 * jt + c;
            float bb = bq[n], bu = pbu[n], bvv = pbv[n];
            #pragma unroll
            for (int j = 0; j < 4; ++j) {
                int m = rbase + j;
                int b_ = m >> 11, t = m & 2047;
                size_t o = (((size_t)(b_ * NHEAD + h)) * TSEQ + t) * HD + d;
                float q = acc[jt][j] + bb;
                qu[o] = (bf16)((q + bu) * SC);
                qv[o] = (bf16)((q + bvv) * SC);
            }
        }
    } else if (mat == 1) {
        #pragma unroll
        for (int jt = 0; jt < 6; ++jt) {
            int n = n0 + 16 * jt + c;
            int d = 16 * jt + c;
            float bb = bk[n];
            #pragma unroll
            for (int j = 0; j < 4; ++j) {
                int m = rbase + j;
                int b_ = m >> 11, t = m & 2047;
                size_t o = (((size_t)(b_ * NHEAD + h)) * TSEQ + t) * HD + d;
                kws[o] = (bf16)(acc[jt][j] + bb);
            }
        }
    } else if (mat == 2) {
        #pragma unroll
        for (int jt = 0; jt < 6; ++jt) {
            int d = 16 * jt + c;
            float bb = bv[n0 + 16 * jt + c];
            int m = rbase;
            int b_ = m >> 11, t0 = m & 2047;
            size_t o = (((size_t)(b_ * NHEAD + h)) * HD + d) * TSEQ + t0;
            bf16x4 pk;
            #pragma unroll
            for (int j = 0; j < 4; ++j) pk[j] = (bf16)(acc[jt][j] + bb);
            *reinterpret_cast<bf16x4*>(vt + o) = pk;
        }
    } else {
        #pragma unroll
        for (int jt = 0; jt < 6; ++jt) {
            int d = 16 * jt + c;
            #pragma unroll
            for (int j = 0; j < 4; ++j) {
                int m = rbase + j;
                if (m < 4095) {
                    size_t o = ((size_t)h * 4096 + m) * HD + d;
                    pp[o] = (bf16)acc[jt][j];
                }
            }
        }
    }
}

// ---------------- fused rel-pos flash attention (KVBLK=128) ----------------
// r16/r18 champion + L2E pre-scale (scores arrive in log2 domain; softmax is
// exp2f(x - m) with no multiply; defer-max THR = 8*log2e = 11.5416).
// K tile [128][104] padded (GL2LDS 13-chunk rows, chunk12=pad); V^T XOR'd;
// win x-indexed quad spill + funnel-shift gather; win between the staging
// barriers covers the DMA drain; acc_s seeded from win gather.
// 256 threads, 2 blocks/CU (LDS 71KB, ~170 combined regs, no spill).
// S^T = mfma(K,Qu): lane(c,g) reg(tk,j) holds S^T[k=16tk+4g+j][q=c].
__launch_bounds__(256, 2)
__global__ void k_attn(const bf16* __restrict__ qu, const bf16* __restrict__ qv,
                       const bf16* __restrict__ kws, const bf16* __restrict__ vt,
                       const bf16* __restrict__ pp, const int* __restrict__ mask,
                       bf16* __restrict__ out) {
    __shared__ bf16 k_lds[128][104];      // K tile, padded rows (2-way banks)
    __shared__ bf16 vt_lds[96][128];      // V^T tile, XOR(ch^(r&7)) chunk layout
    __shared__ bf16 wp_lds[4][16][168];   // win (x-indexed quads) / P — time-phased

    int bid = blockIdx.x;
    int x = bid & 7, j5 = bid >> 3;
    int h = x & 3;
    int b_ = (x >> 2) * 4 + (j5 >> 5);
    int qb = j5 & 31;
    int bh = b_ * NHEAD + h;
    int q0 = qb * 64;

    int tid = threadIdx.x, lane = tid & 63, w = tid >> 6;
    int c = lane & 15, g = lane >> 4;
    const int NB = 2032 - q0 - 16 * w;    // wave's win-band base (kt=0)

    // ---- kt-invariant staging coordinates (named scalars) ----
    bf16* k_flat = &k_lds[0][0];
    bf16* vt_flat = &vt_lds[0][0];
    int cc0 = tid, cc1 = tid + 256, cc2 = tid + 512, cc3 = tid + 768;
    int cc4 = tid + 1024, cc5 = tid + 1280, cc6 = tid + 1536;
    int kr0 = cc0 / 13, kc0 = cc0 % 13;  int kO0 = kr0 * HD + (kc0 == 12 ? 0 : kc0 * 8);
    int kr1 = cc1 / 13, kc1 = cc1 % 13;  int kO1 = kr1 * HD + (kc1 == 12 ? 0 : kc1 * 8);
    int kr2 = cc2 / 13, kc2 = cc2 % 13;  int kO2 = kr2 * HD + (kc2 == 12 ? 0 : kc2 * 8);
    int kr3 = cc3 / 13, kc3 = cc3 % 13;  int kO3 = kr3 * HD + (kc3 == 12 ? 0 : kc3 * 8);
    int kr4 = cc4 / 13, kc4 = cc4 % 13;  int kO4 = kr4 * HD + (kc4 == 12 ? 0 : kc4 * 8);
    int kr5 = cc5 / 13, kc5 = cc5 % 13;  int kO5 = kr5 * HD + (kc5 == 12 ? 0 : kc5 * 8);
    int kr6 = cc6 / 13, kc6 = cc6 % 13;  int kO6 = kr6 * HD + (kc6 == 12 ? 0 : kc6 * 8);
    bf16* kL0 = k_flat + (size_t)(64 * w + 0)    * 8;
    bf16* kL1 = k_flat + (size_t)(64 * w + 256)  * 8;
    bf16* kL2 = k_flat + (size_t)(64 * w + 512)  * 8;
    bf16* kL3 = k_flat + (size_t)(64 * w + 768)  * 8;
    bf16* kL4 = k_flat + (size_t)(64 * w + 1024) * 8;
    bf16* kL5 = k_flat + (size_t)(64 * w + 1280) * 8;
    bf16* kL6 = k_flat + (size_t)(64 * w + 1536) * 8;
    bool kAct6 = (w < 2);                 // cc6 < 1664 wave-uniform
    int vr0 = cc0 >> 4, vc0 = cc0 & 15;  int vO0 = vr0 * TSEQ + (vc0 ^ (vr0 & 7)) * 8;
    int vr1 = cc1 >> 4, vc1 = cc1 & 15;  int vO1 = vr1 * TSEQ + (vc1 ^ (vr1 & 7)) * 8;
    int vr2 = cc2 >> 4, vc2 = cc2 & 15;  int vO2 = vr2 * TSEQ + (vc2 ^ (vr2 & 7)) * 8;
    int vr3 = cc3 >> 4, vc3 = cc3 & 15;  int vO3 = vr3 * TSEQ + (vc3 ^ (vr3 & 7)) * 8;
    int vr4 = cc4 >> 4, vc4 = cc4 & 15;  int vO4 = vr4 * TSEQ + (vc4 ^ (vr4 & 7)) * 8;
    int vr5 = cc5 >> 4, vc5 = cc5 & 15;  int vO5 = vr5 * TSEQ + (vc5 ^ (vr5 & 7)) * 8;
    bf16* vL0 = vt_flat + (size_t)(64 * w + 0)    * 8;
    bf16* vL1 = vt_flat + (size_t)(64 * w + 256)  * 8;
    bf16* vL2 = vt_flat + (size_t)(64 * w + 512)  * 8;
    bf16* vL3 = vt_flat + (size_t)(64 * w + 768)  * 8;
    bf16* vL4 = vt_flat + (size_t)(64 * w + 1024) * 8;
    bf16* vL5 = vt_flat + (size_t)(64 * w + 1280) * 8;

    const bf16* kbP = kws + (size_t)bh * TSEQ * HD;
    const bf16* vbP = vt + (size_t)bh * HD * TSEQ;
    const bf16* pbP = pp + (size_t)h * 4096 * HD;
    const int*  mbP = mask + b_ * TSEQ;

    bf16x8 qu_f[3], qv_f[3];
    {
        size_t rowbase = ((size_t)bh * TSEQ + q0 + 16 * w + c) * HD + 8 * g;
        #pragma unroll
        for (int ds = 0; ds < 3; ++ds) {
            qu_f[ds] = *reinterpret_cast<const bf16x8*>(qu + rowbase + 32 * ds);
            qv_f[ds] = *reinterpret_cast<const bf16x8*>(qv + rowbase + 32 * ds);
        }
    }

    f32x4 acc_o[6] = {};
    float mrow = -3.0e38f, lrow = 0.f;
    f32x4 wc;          // win carry: tile8 of iter kt == tile0 of kt+1
    int   mk0, mk1;    // pipelined mask words for the CURRENT tile

    bf16* wp_row = &wp_lds[w][c][0];
    const int hc = (15 - c) >> 2;         // gather quad offset
    const int sh = ((15 - c) & 3) * 16;   // gather funnel-shift (bits)

    // ---- compute+spill a PAIR of win tiles (aligned bf16x4 stores) ----
    auto winpair = [&](int wb, int ta, int tb) {
        f32x4 wa = {}, wbv = {};
        const bf16* pa = pbP + (size_t)(wb + 16 * ta + c) * HD + 8 * g;
        const bf16* pb = pbP + (size_t)(wb + 16 * tb + c) * HD + 8 * g;
        __builtin_amdgcn_s_setprio(1);
        #pragma unroll
        for (int ds = 0; ds < 3; ++ds) {
            wa  = mfma16(*reinterpret_cast<const bf16x8*>(pa + 32 * ds), qv_f[ds], wa);
            wbv = mfma16(*reinterpret_cast<const bf16x8*>(pb + 32 * ds), qv_f[ds], wbv);
        }
        __builtin_amdgcn_s_setprio(0);
        bf16x4 qa, qb;
        #pragma unroll
        for (int j = 0; j < 4; ++j) { qa[j] = (bf16)wa[j]; qb[j] = (bf16)wbv[j]; }
        *reinterpret_cast<bf16x4*>(wp_row + 16 * ta + 4 * g) = qa;
        *reinterpret_cast<bf16x4*>(wp_row + 16 * tb + 4 * g) = qb;
        return wbv;
    };

    // ---- prologue: stage tile 0 (K+V DMA), mask, win[0] tiles 0..8 ----
    {
        GL2LDS(kbP + kO0, kL0); GL2LDS(kbP + kO1, kL1); GL2LDS(kbP + kO2, kL2);
        GL2LDS(kbP + kO3, kL3); GL2LDS(kbP + kO4, kL4); GL2LDS(kbP + kO5, kL5);
        if (kAct6) GL2LDS(kbP + kO6, kL6);
        GL2LDS(vbP + vO0, vL0); GL2LDS(vbP + vO1, vL1); GL2LDS(vbP + vO2, vL2);
        GL2LDS(vbP + vO3, vL3); GL2LDS(vbP + vO4, vL4); GL2LDS(vbP + vO5, vL5);
        mk0 = mbP[lane]; mk1 = mbP[64 + lane];

        {   // tile 0
            f32x4 w0 = {};
            const bf16* p0 = pbP + (size_t)(NB + c) * HD + 8 * g;
            #pragma unroll
            for (int ds = 0; ds < 3; ++ds)
                w0 = mfma16(*reinterpret_cast<const bf16x8*>(p0 + 32 * ds), qv_f[ds], w0);
            bf16x4 q0v;
            #pragma unroll
            for (int j = 0; j < 4; ++j) q0v[j] = (bf16)w0[j];
            *reinterpret_cast<bf16x4*>(wp_row + 4 * g) = q0v;
        }
        winpair(NB, 1, 2);
        winpair(NB, 3, 4);
        winpair(NB, 5, 6);
        wc = winpair(NB, 7, 8);
    }
    __syncthreads();  // drains vmcnt (K/V DMA) + lgkm (win spills)

    for (int kt = 0; kt < 16; ++kt) {
        unsigned long long bm0 = __ballot(mk0 != 0);
        unsigned long long bm1 = __ballot(mk1 != 0);

        // ---- gather win[kt]: 2 aligned b64 + funnel shift per tile ----
        bf16x4 wv[8];
        #pragma unroll
        for (int tk = 0; tk < 8; ++tk) {
            int qd = 4 * tk + g + hc;
            u64 A8 = *reinterpret_cast<const u64*>(wp_row + 4 * qd);
            u64 B8 = *reinterpret_cast<const u64*>(wp_row + 4 * qd + 4);
            u64 o8 = sh ? ((A8 >> sh) | (B8 << (64 - sh))) : A8;
            *reinterpret_cast<u64*>(&wv[tk]) = o8;
        }

        // ---- content scores S^T: acc_s seeded with win (MFMA adds for free)
        f32x4 acc_s[8];
        #pragma unroll
        for (int tk = 0; tk < 8; ++tk)
            acc_s[tk] = f32x4{(float)wv[tk][0], (float)wv[tk][1],
                              (float)wv[tk][2], (float)wv[tk][3]};
        __builtin_amdgcn_s_setprio(1);
        #pragma unroll
        for (int ds = 0; ds < 3; ++ds) {
            #pragma unroll
            for (int tk = 0; tk < 8; ++tk) {
                bf16x8 a = *reinterpret_cast<const bf16x8*>(
                    &k_lds[16 * tk + c][32 * ds + 8 * g]);
                acc_s[tk] = mfma16(a, qu_f[ds], acc_s[tk]);
            }
        }
        __builtin_amdgcn_s_setprio(0);

        // ---- mask + online softmax in log2 domain (per-lane row q=c) ----
        if ((bm0 & bm1) != ~0ull) {
            #pragma unroll
            for (int tk = 0; tk < 8; ++tk) {
                unsigned long long bb = (tk < 4) ? bm0 : bm1;
                int base = 16 * (tk & 3) + 4 * g;
                #pragma unroll
                for (int j = 0; j < 4; ++j)
                    if (!((bb >> (base + j)) & 1)) acc_s[tk][j] = -3.0e38f;
            }
        }
        float pm = acc_s[0][0];
        #pragma unroll
        for (int tk = 0; tk < 8; ++tk)
            #pragma unroll
            for (int j = 0; j < 4; ++j) pm = fmaxf(pm, acc_s[tk][j]);
        pm = fmaxf(pm, __shfl_xor(pm, 16));
        pm = fmaxf(pm, __shfl_xor(pm, 32));
        if (!__all(pm <= mrow + 11.5415603f)) {   // defer-max (THR=8*log2e)
            float mnew = fmaxf(mrow, pm);
            float alpha = exp2f(mrow - mnew);
            mrow = mnew; lrow *= alpha;
            #pragma unroll
            for (int ot = 0; ot < 6; ++ot) acc_o[ot] *= alpha;
        }
        float rs = 0.f;
        #pragma unroll
        for (int tk = 0; tk < 8; ++tk)
            #pragma unroll
            for (int j = 0; j < 4; ++j) {
                float p = exp2f(acc_s[tk][j] - mrow);
                acc_s[tk][j] = p; rs += p;
            }
        rs += __shfl_xor(rs, 16);
        rs += __shfl_xor(rs, 32);
        lrow += rs;

        // ---- P -> LDS (col-major [q][k], aligned b64) ----
        #pragma unroll
        for (int tk = 0; tk < 8; ++tk) {
            bf16x4 pk;
            #pragma unroll
            for (int j = 0; j < 4; ++j) pk[j] = (bf16)acc_s[tk][j];
            *reinterpret_cast<bf16x4*>(wp_row + 16 * tk + 4 * g) = pk;
        }
        LDS_HANDOFF();  // P spills -> PV B-frags (cross-lane, same wave)

        // ---- PV: O^T += V^T . P ----
        __builtin_amdgcn_s_setprio(1);
        #pragma unroll
        for (int ds = 0; ds < 4; ++ds) {
            bf16x8 pb_ = *reinterpret_cast<const bf16x8*>(wp_row + 32 * ds + 8 * g);
            #pragma unroll
            for (int ot = 0; ot < 6; ++ot) {
                int rr = 16 * ot + c;
                bf16x8 a = *reinterpret_cast<const bf16x8*>(
                    &vt_lds[rr][(((4 * ds + g) ^ (rr & 7)) * 8)]);
                acc_o[ot] = mfma16(a, pb_, acc_o[ot]);
            }
        }
        __builtin_amdgcn_s_setprio(0);

        if (kt < 15) {
            __syncthreads();  // barrier1: all waves done reading tile kt

            // ---- issue K+V DMA for tile kt+1 FIRST (latency hidden by win) ----
            int k0n = (kt + 1) * 128;
            const bf16* kb = kbP + (size_t)k0n * HD;
            const bf16* vb = vbP + k0n;
            GL2LDS(kb + kO0, kL0); GL2LDS(kb + kO1, kL1); GL2LDS(kb + kO2, kL2);
            GL2LDS(kb + kO3, kL3); GL2LDS(kb + kO4, kL4); GL2LDS(kb + kO5, kL5);
            if (kAct6) GL2LDS(kb + kO6, kL6);
            GL2LDS(vb + vO0, vL0); GL2LDS(vb + vO1, vL1); GL2LDS(vb + vO2, vL2);
            GL2LDS(vb + vO3, vL3); GL2LDS(vb + vO4, vL4); GL2LDS(vb + vO5, vL5);
            mk0 = mbP[k0n + lane]; mk1 = mbP[k0n + 64 + lane];

            // ---- win[kt+1]: carry as tile0 (aligned), tiles 1..8 in pairs ----
            int wb = NB + 128 * (kt + 1);
            bf16x4 q0v;
            #pragma unroll
            for (int j = 0; j < 4; ++j) q0v[j] = (bf16)wc[j];
            *reinterpret_cast<bf16x4*>(wp_row + 4 * g) = q0v;
            winpair(wb, 1, 2);
            winpair(wb, 3, 4);
            winpair(wb, 5, 6);
            wc = winpair(wb, 7, 8);

            __syncthreads();  // barrier2: vmcnt mostly drained under win compute
        }
    }

    // ---- epilogue ----
    float inv = 1.0f / lrow;
    size_t m = (size_t)b_ * TSEQ + q0 + 16 * w + c;
    bf16* ob = out + m * HID + h * HD + 4 * g;
    #pragma unroll
    for (int ot = 0; ot < 6; ++ot) {
        bf16x4 pk;
        #pragma unroll
        for (int j = 0; j < 4; ++j) pk[j] = (bf16)(acc_o[ot][j] * inv);
        *reinterpret_cast<bf16x4*>(&ob[16 * ot]) = pk;
    }
}

// ---------------- output projection ----------------
__launch_bounds__(256, 2)
__global__ void k_oproj(const bf16* __restrict__ A, const bf16* __restrict__ WT,
                        const float* __restrict__ bias, float* __restrict__ out) {
    __shared__ bf16 wt_lds[96][392];
    int m0 = blockIdx.x * 64, n0 = blockIdx.y * 96;
    int tid = threadIdx.x;
    #pragma unroll
    for (int s = 0; s < 18; ++s) {
        int cc = tid + 256 * s;
        int r = cc / 48, ch = cc % 48;
        *reinterpret_cast<int4*>(&wt_lds[r][ch * 8]) =
            *reinterpret_cast<const int4*>(WT + (size_t)(n0 + r) * HID + ch * 8);
    }
    __syncthreads();
    int lane = tid & 63, w = tid >> 6;
    int c = lane & 15, g = lane >> 4;
    const bf16* Abase = A + (size_t)(m0 + 16 * w + c) * HID + 8 * g;
    f32x4 acc[6] = {};
    for (int ks = 0; ks < 12; ++ks) {
        bf16x8 a = *reinterpret_cast<const bf16x8*>(Abase + 32 * ks);
        #pragma unroll
        for (int jt = 0; jt < 6; ++jt) {
            bf16x8 b = *reinterpret_cast<const bf16x8*>(&wt_lds[16 * jt + c][32 * ks + 8 * g]);
            acc[jt] = mfma16(a, b, acc[jt]);
        }
    }
    int rbase = m0 + 16 * w + 4 * g;
    #pragma unroll
    for (int jt = 0; jt < 6; ++jt) {
        int n = n0 + 16 * jt + c;
        float bb = bias[n];
        #pragma unroll
        for (int j = 0; j < 4; ++j)
            out[(size_t)(rbase + j) * HID + n] = acc[jt][j] + bb;
    }
}

extern "C" void kernel_launch(void* const* d_in, const int* in_sizes, int n_in,
                              void* d_out, int out_size, void* d_ws, size_t ws_size,
                              hipStream_t stream) {
    const float* hs  = (const float*)d_in[0];
    const float* pe  = (const float*)d_in[1];
    const int*   msk = (const int*)d_in[2];
    const float* Wq  = (const float*)d_in[3];
    const float* bq  = (const float*)d_in[4];
    const float* Wk  = (const float*)d_in[5];
    const float* bk  = (const float*)d_in[6];
    const float* Wv  = (const float*)d_in[7];
    const float* bv  = (const float*)d_in[8];
    const float* Wo  = (const float*)d_in[9];
    const float* bo  = (const float*)d_in[10];
    const float* Wp  = (const float*)d_in[11];
    const float* pbu = (const float*)d_in[12];
    const float* pbv = (const float*)d_in[13];

    char* ws = (char*)d_ws;
    size_t off = 0;
    auto alloc = [&](size_t b) { char* p = ws + off; off += (b + 255) & ~(size_t)255; return p; };
    bf16* Xb  = (bf16*)alloc((size_t)16384 * HID * 2);
    bf16* Pb  = (bf16*)alloc((size_t)4096 * HID * 2);
    bf16* wqT = (bf16*)alloc((size_t)HID * HID * 2);
    bf16* wkT = (bf16*)alloc((size_t)HID * HID * 2);
    bf16* wvT = (bf16*)alloc((size_t)HID * HID * 2);
    bf16* woT = (bf16*)alloc((size_t)HID * HID * 2);
    bf16* wpT = (bf16*)alloc((size_t)HID * HID * 2);
    bf16* qu  = (bf16*)alloc((size_t)NBATCH * NHEAD * TSEQ * HD * 2);
    bf16* qv  = (bf16*)alloc((size_t)NBATCH * NHEAD * TSEQ * HD * 2);
    bf16* kws = (bf16*)alloc((size_t)NBATCH * NHEAD * TSEQ * HD * 2);
    bf16* vt  = (bf16*)alloc((size_t)NBATCH * NHEAD * TSEQ * HD * 2);
    bf16* pp  = (bf16*)alloc((size_t)NHEAD * 4096 * HD * 2 + 65536);  // +slack
    bf16* ao  = (bf16*)alloc((size_t)16384 * HID * 2);

    k_conv8m<<<3840, 256, 0, stream>>>(hs, Xb, pe, Pb);
    k_convT5<<<dim3(576, 5), 256, 0, stream>>>(Wq, Wk, Wv, Wo, Wp,
                                               wqT, wkT, wvT, woT, wpT);
    k_proj<<<dim3(256, 4, 4), 256, 0, stream>>>(Xb, Pb, wqT, wkT, wvT, wpT,
                                                bq, bk, bv, pbu, pbv,
                                                qu, qv, kws, vt, pp);
    k_attn<<<1024, 256, 0, stream>>>(qu, qv, kws, vt, pp, msk, ao);
    k_oproj<<<dim3(256, 4), 256, 0, stream>>>(ao, woT, bo, (float*)d_out);
}